// Round 5
// baseline (820.197 us; speedup 1.0000x reference)
//
#include <hip/hip_runtime.h>
#include <cmath>

#define B_ 32
#define N_ 64
#define H_ 256
#define G3_ 768           // 3*H
#define INTER_ 912        // 2H + 6C + C1
#define FCIN_ 2992        // 3*INTER + H

#define PADA 264          // hA row stride (bf16 elems), 528 B (16B-aligned)
#define PADX 72           // xA row stride (bf16 elems), 144 B

typedef __attribute__((ext_vector_type(8))) short short8;
typedef __attribute__((ext_vector_type(4))) float float4v;

__device__ __forceinline__ float sigmoid_f(float x) {
    return __fdividef(1.0f, 1.0f + __expf(-x));
}
__device__ __forceinline__ float tanh_fast(float x) {
    x = fminf(fmaxf(x, -15.f), 15.f);
    float e = __expf(2.f * x);
    return 1.f - __fdividef(2.f, e + 1.f);
}
__device__ __forceinline__ unsigned f2bf_bits(float x) {
    unsigned u = __float_as_uint(x);
    return (u + 0x7fffu + ((u >> 16) & 1u)) >> 16;
}
__device__ __forceinline__ short f2bf(float x) { return (short)f2bf_bits(x); }

// ---------------------------------------------------------------------------
// prep: (a) Bfrag  = gru2d weights, fragment-major bf16 (layout verified R2)
//       (b) Bfrag1 = gru1d Whh, same fragment-major pack (8 kt)
//       (c) fc1Wt transpose
// Fragment layout: [kt][ntile(48)][lane(64)][j(8)] bf16; value = W[n][k] with
// n = ntile*16 + (lane&15), k = kt*32 + (lane>>4)*8 + j.
// ---------------------------------------------------------------------------
__global__ __launch_bounds__(256) void prep_kernel(
        const float* __restrict__ Whh2, const float* __restrict__ Wih2,
        const float* __restrict__ Whh1, const float* __restrict__ fc1W,
        short* __restrict__ Bfrag, short* __restrict__ Bfrag1,
        float* __restrict__ fc1Wt) {
    int idx = blockIdx.x * 256 + threadIdx.x;
    if (idx < 10 * 48 * 64 * 8) {
        int j = idx & 7, lane = (idx >> 3) & 63, tile = idx >> 9;
        int nt = tile % 48, kt = tile / 48;
        int n = nt * 16 + (lane & 15);
        int kb = (lane >> 4) * 8 + j;
        float v = (kt < 8) ? Whh2[n * 256 + kt * 32 + kb]
                           : Wih2[n * 64 + (kt - 8) * 32 + kb];
        Bfrag[idx] = f2bf(v);
    }
    if (idx < 8 * 48 * 64 * 8) {
        int j = idx & 7, lane = (idx >> 3) & 63, tile = idx >> 9;
        int nt = tile % 48, kt = tile / 48;
        int n = nt * 16 + (lane & 15);
        int k = kt * 32 + (lane >> 4) * 8 + j;
        Bfrag1[idx] = f2bf(Whh1[n * 256 + k]);
    }
    if (idx < FCIN_ * 256) {
        int o = idx & 255, i = idx >> 8;
        fc1Wt[idx] = fc1W[o * FCIN_ + i];
    }
}

// ---------------------------------------------------------------------------
// reduce_states: d[] reductions + x1 copy -> f[:, 0:400]
// ---------------------------------------------------------------------------
__global__ __launch_bounds__(256) void reduce_states_kernel(
        const float* __restrict__ states, const float* __restrict__ x1,
        float* __restrict__ f) {
    const int c = threadIdx.x & 63;
    const int bj = blockIdx.x * 4 + (threadIdx.x >> 6);
    const int b = bj >> 6, j = bj & 63;
    const float* p1 = states + b * 262144 + j * 64 + c;
    const float* p2 = states + b * 262144 + j * 4096 + c;
    float mx1 = -1e30f, mn1 = 1e30f, sm1 = 0.f;
    float mx2 = -1e30f, mn2 = 1e30f, sm2 = 0.f;
    #pragma unroll 8
    for (int n = 0; n < 64; ++n) {
        float v = p1[n * 4096];
        mx1 = fmaxf(mx1, v); mn1 = fminf(mn1, v); sm1 += v;
    }
    #pragma unroll 8
    for (int m = 0; m < 64; ++m) {
        float v = p2[m * 64];
        mx2 = fmaxf(mx2, v); mn2 = fminf(mn2, v); sm2 += v;
    }
    float* fr = f + bj * INTER_;
    fr[16 + c]  = mx1;  fr[80 + c]  = sm1 * (1.f / 64.f);  fr[144 + c] = mn1;
    fr[208 + c] = mx2;  fr[272 + c] = sm2 * (1.f / 64.f);  fr[336 + c] = mn2;
    if (c < 16) fr[c] = x1[bj * 16 + c];
}

// ---------------------------------------------------------------------------
// gru2d via MFMA bf16, 16-wave edition. 256 blocks x 1024 threads (4 waves/EU).
// Block owns 16 seqs. Wave w owns 3 N-tiles: r-tile w, z-tile 16+w, n-tile
// 32+w -> thread (w,lane) owns unit u=16w+(lane&15), rows q*4..q*4+3, with all
// four preacts (r,z,nh,nx) in its own accumulators. B: kt0..5 in 72 VGPRs,
// kt6..7 in 96 KB LDS, kt8..9 (x-part) VMEM per step (L2-hot).
// hA double-buffered -> ONE barrier per step. x-gather: 1 load/thread/step.
// ---------------------------------------------------------------------------
__global__ __launch_bounds__(1024) void gru2d_mfma(
        const float* __restrict__ states,
        const int* __restrict__ perm1, const int* __restrict__ perm2,
        const short* __restrict__ Bfrag,
        const float* __restrict__ bih, const float* __restrict__ bhh,
        float* __restrict__ f) {
    __shared__ short hA[2][16 * PADA];     // 16896 B, double-buffered
    __shared__ short xA[2][16 * PADX];     // 4608 B, double-buffered
    __shared__ short8 Blds[2 * 48 * 64];   // 98304 B: kt 6,7
    __shared__ int perms[1024];            // 4096 B

    const int tid = threadIdx.x;
    const int lane = tid & 63;
    const int w = tid >> 6;                // wave 0..15
    const int m = lane & 15;
    const int q = lane >> 4;
    const bool sd2 = blockIdx.x >= 128;
    const int sblock = (blockIdx.x & 127) * 16;

    // perms: thread tid serves (r = tid>>6, t = tid&63); only its own wave
    // reads perms[w*64 + t], so no barrier needed for the t=0 gather below.
    {
        int r = tid >> 6, t = tid & 63;
        int qq = (sblock + r) & 63;
        perms[tid] = sd2 ? perm2[qq * 64 + t] : perm1[qq * 64 + t];
    }
    for (int i = tid; i < 16 * PADA; i += 1024) hA[0][i] = 0;
    {   // Blds <- kt 6,7 slice of Bfrag (contiguous)
        const uint4* src = (const uint4*)(Bfrag + 6 * 48 * 64 * 8);
        uint4* dst = (uint4*)Blds;
        #pragma unroll
        for (int rep = 0; rep < 6; ++rep)
            dst[tid + rep * 1024] = src[tid + rep * 1024];
    }

    const short8* Bf8 = (const short8*)Bfrag;
    short8 Bres[18];                       // kt0..5 x {r,z,n} tiles
    #pragma unroll
    for (int kt = 0; kt < 6; ++kt) {
        Bres[kt * 3 + 0] = Bf8[(kt * 48 + w) * 64 + lane];
        Bres[kt * 3 + 1] = Bf8[(kt * 48 + 16 + w) * 64 + lane];
        Bres[kt * 3 + 2] = Bf8[(kt * 48 + 32 + w) * 64 + lane];
    }

    const int u = 16 * w + m;
    const float br  = bih[u] + bhh[u];
    const float bz  = bih[256 + u] + bhh[256 + u];
    const float bnx = bih[512 + u];
    const float bnh = bhh[512 + u];

    float4v hreg = {0.f, 0.f, 0.f, 0.f};

    // gather geometry for this thread (row r == wave id, col c == lane)
    const int gr = w, gc = lane;
    const int gs = sblock + gr, gb = gs >> 6, gq = gs & 63;
    const int xdst = gr * PADX + gc;

    {   // stage x for t=0
        int p = perms[gr * 64 + 0];
        int src = sd2 ? ((gb * 64 + p) * 64 + gq) * 64 + gc
                      : ((gb * 64 + gq) * 64 + p) * 64 + gc;
        xA[0][xdst] = f2bf(states[src]);
    }
    __syncthreads();

    for (int t = 0; t < 64; ++t) {
        // issue next-step x gather early (lands during MFMA phase)
        float xg = 0.f;
        if (t + 1 < 64) {
            int p = perms[gr * 64 + t + 1];
            int src = sd2 ? ((gb * 64 + p) * 64 + gq) * 64 + gc
                          : ((gb * 64 + gq) * 64 + p) * 64 + gc;
            xg = states[src];
        }

        float4v aR  = {0.f,0.f,0.f,0.f}, aZ  = {0.f,0.f,0.f,0.f};
        float4v aNh = {0.f,0.f,0.f,0.f}, aNx = {0.f,0.f,0.f,0.f};

        const short* hACur = hA[t & 1];
        // h-phase, VGPR-resident kt0..5
        #pragma unroll
        for (int kt = 0; kt < 6; ++kt) {
            short8 a = *(const short8*)(hACur + m * PADA + kt * 32 + q * 8);
            aR  = __builtin_amdgcn_mfma_f32_16x16x32_bf16(a, Bres[kt*3+0], aR, 0,0,0);
            aZ  = __builtin_amdgcn_mfma_f32_16x16x32_bf16(a, Bres[kt*3+1], aZ, 0,0,0);
            aNh = __builtin_amdgcn_mfma_f32_16x16x32_bf16(a, Bres[kt*3+2], aNh, 0,0,0);
        }
        // x-part B loads, batch kt8 (cover with LDS-B phase)
        short8 bx80 = Bf8[(8 * 48 + w) * 64 + lane];
        short8 bx81 = Bf8[(8 * 48 + 16 + w) * 64 + lane];
        short8 bx82 = Bf8[(8 * 48 + 32 + w) * 64 + lane];
        // h-phase, LDS-resident kt6,7
        #pragma unroll
        for (int ktL = 0; ktL < 2; ++ktL) {
            short8 a = *(const short8*)(hACur + m * PADA + (6 + ktL) * 32 + q * 8);
            short8 b0 = Blds[(ktL * 48 + w) * 64 + lane];
            short8 b1 = Blds[(ktL * 48 + 16 + w) * 64 + lane];
            short8 b2 = Blds[(ktL * 48 + 32 + w) * 64 + lane];
            aR  = __builtin_amdgcn_mfma_f32_16x16x32_bf16(a, b0, aR, 0,0,0);
            aZ  = __builtin_amdgcn_mfma_f32_16x16x32_bf16(a, b1, aZ, 0,0,0);
            aNh = __builtin_amdgcn_mfma_f32_16x16x32_bf16(a, b2, aNh, 0,0,0);
        }
        // x-part B loads, batch kt9
        short8 bx90 = Bf8[(9 * 48 + w) * 64 + lane];
        short8 bx91 = Bf8[(9 * 48 + 16 + w) * 64 + lane];
        short8 bx92 = Bf8[(9 * 48 + 32 + w) * 64 + lane];
        // x-phase kt8,9
        {
            const short* xACur = xA[t & 1];
            short8 a8 = *(const short8*)(xACur + m * PADX + q * 8);
            aR  = __builtin_amdgcn_mfma_f32_16x16x32_bf16(a8, bx80, aR, 0,0,0);
            aZ  = __builtin_amdgcn_mfma_f32_16x16x32_bf16(a8, bx81, aZ, 0,0,0);
            aNx = __builtin_amdgcn_mfma_f32_16x16x32_bf16(a8, bx82, aNx, 0,0,0);
            short8 a9 = *(const short8*)(xACur + m * PADX + 32 + q * 8);
            aR  = __builtin_amdgcn_mfma_f32_16x16x32_bf16(a9, bx90, aR, 0,0,0);
            aZ  = __builtin_amdgcn_mfma_f32_16x16x32_bf16(a9, bx91, aZ, 0,0,0);
            aNx = __builtin_amdgcn_mfma_f32_16x16x32_bf16(a9, bx92, aNx, 0,0,0);
        }

        // commit next-step x to the other buffer
        if (t + 1 < 64) xA[(t + 1) & 1][xdst] = f2bf(xg);

        // register-local GRU update; write h(t+1) into the other hA buffer
        short* hANext = hA[(t + 1) & 1];
        #pragma unroll
        for (int p = 0; p < 4; ++p) {
            int row = q * 4 + p;
            float r_ = sigmoid_f(aR[p] + br);
            float z_ = sigmoid_f(aZ[p] + bz);
            float n_ = tanh_fast(aNx[p] + bnx + r_ * (aNh[p] + bnh));
            float hn = (1.f - z_) * n_ + z_ * hreg[p];
            hreg[p] = hn;
            hANext[row * PADA + u] = f2bf(hn);
        }
        __syncthreads();   // h(t+1), x(t+1) visible; everyone leaves step t
    }

    const int off = sd2 ? 656 : 400;
    #pragma unroll
    for (int p = 0; p < 4; ++p) {
        int s = sblock + q * 4 + p;
        f[s * INTER_ + off + u] = hreg[p];
    }
}

// ---------------------------------------------------------------------------
// xw1[2048][768] = f[2048][912] @ Wih1^T + bih1  (fp32 tiled GEMM)
// ---------------------------------------------------------------------------
__global__ __launch_bounds__(256) void gemm_xw1(
        const float* __restrict__ f, const float* __restrict__ Wih,
        const float* __restrict__ bih, float* __restrict__ xw) {
    __shared__ float As[64][17];
    __shared__ float Bs[64][17];
    const int tid = threadIdx.x;
    const int tn = blockIdx.x;
    const int tm = blockIdx.y;
    const int tx = tid & 15, ty = tid >> 4;
    float acc[4][4] = {};
    for (int k0 = 0; k0 < INTER_; k0 += 16) {
        for (int i = tid; i < 64 * 16; i += 256) {
            int r = i >> 4, kk = i & 15;
            As[r][kk] = f[(tm * 64 + r) * INTER_ + k0 + kk];
            Bs[r][kk] = Wih[(tn * 64 + r) * INTER_ + k0 + kk];
        }
        __syncthreads();
        #pragma unroll
        for (int kk = 0; kk < 16; ++kk) {
            float a[4], bb[4];
            #pragma unroll
            for (int i = 0; i < 4; ++i) a[i] = As[ty * 4 + i][kk];
            #pragma unroll
            for (int j = 0; j < 4; ++j) bb[j] = Bs[tx * 4 + j][kk];
            #pragma unroll
            for (int i = 0; i < 4; ++i)
                #pragma unroll
                for (int j = 0; j < 4; ++j)
                    acc[i][j] = fmaf(a[i], bb[j], acc[i][j]);
        }
        __syncthreads();
    }
    #pragma unroll
    for (int i = 0; i < 4; ++i) {
        int row = tm * 64 + ty * 4 + i;
        #pragma unroll
        for (int j = 0; j < 4; ++j) {
            int col = tn * 64 + tx * 4 + j;
            xw[row * G3_ + col] = acc[i][j] + bih[col];
        }
    }
}

// ---------------------------------------------------------------------------
// gru1d via MFMA bf16, 16-wave edition. 2 blocks x 1024 threads; block owns
// 16 sequences. gi (x-part incl. bih) from xw1, prefetched at step top.
// Same wave->tile mapping as gru2d; hA double-buffered, one barrier/step.
// ---------------------------------------------------------------------------
__global__ __launch_bounds__(1024) void gru1d_mfma(
        const float* __restrict__ xw, const short* __restrict__ Bfrag1,
        const float* __restrict__ bhh, float* __restrict__ hlast) {
    __shared__ short hA[2][16 * PADA];
    __shared__ short8 Blds[2 * 48 * 64];   // kt 6,7

    const int tid = threadIdx.x;
    const int lane = tid & 63;
    const int w = tid >> 6;
    const int m = lane & 15;
    const int q = lane >> 4;
    const int sblock = blockIdx.x * 16;

    for (int i = tid; i < 16 * PADA; i += 1024) hA[0][i] = 0;
    {
        const uint4* src = (const uint4*)(Bfrag1 + 6 * 48 * 64 * 8);
        uint4* dst = (uint4*)Blds;
        #pragma unroll
        for (int rep = 0; rep < 6; ++rep)
            dst[tid + rep * 1024] = src[tid + rep * 1024];
    }
    const short8* Bf8 = (const short8*)Bfrag1;
    short8 Bres[18];
    #pragma unroll
    for (int kt = 0; kt < 6; ++kt) {
        Bres[kt * 3 + 0] = Bf8[(kt * 48 + w) * 64 + lane];
        Bres[kt * 3 + 1] = Bf8[(kt * 48 + 16 + w) * 64 + lane];
        Bres[kt * 3 + 2] = Bf8[(kt * 48 + 32 + w) * 64 + lane];
    }

    const int u = 16 * w + m;
    const float bhr = bhh[u], bhz = bhh[256 + u], bhn = bhh[512 + u];

    float4v hreg = {0.f, 0.f, 0.f, 0.f};
    __syncthreads();

    for (int t = 0; t < 64; ++t) {
        // prefetch gi (L2-hot, covered by the MFMA phase)
        float giR[4], giZ[4], giN[4];
        #pragma unroll
        for (int p = 0; p < 4; ++p) {
            const float* g = xw + ((sblock + q * 4 + p) * 64 + t) * G3_;
            giR[p] = g[u]; giZ[p] = g[256 + u]; giN[p] = g[512 + u];
        }

        float4v aR = {0.f,0.f,0.f,0.f}, aZ = {0.f,0.f,0.f,0.f};
        float4v aN = {0.f,0.f,0.f,0.f};

        const short* hACur = hA[t & 1];
        #pragma unroll
        for (int kt = 0; kt < 6; ++kt) {
            short8 a = *(const short8*)(hACur + m * PADA + kt * 32 + q * 8);
            aR = __builtin_amdgcn_mfma_f32_16x16x32_bf16(a, Bres[kt*3+0], aR, 0,0,0);
            aZ = __builtin_amdgcn_mfma_f32_16x16x32_bf16(a, Bres[kt*3+1], aZ, 0,0,0);
            aN = __builtin_amdgcn_mfma_f32_16x16x32_bf16(a, Bres[kt*3+2], aN, 0,0,0);
        }
        #pragma unroll
        for (int ktL = 0; ktL < 2; ++ktL) {
            short8 a = *(const short8*)(hACur + m * PADA + (6 + ktL) * 32 + q * 8);
            short8 b0 = Blds[(ktL * 48 + w) * 64 + lane];
            short8 b1 = Blds[(ktL * 48 + 16 + w) * 64 + lane];
            short8 b2 = Blds[(ktL * 48 + 32 + w) * 64 + lane];
            aR = __builtin_amdgcn_mfma_f32_16x16x32_bf16(a, b0, aR, 0,0,0);
            aZ = __builtin_amdgcn_mfma_f32_16x16x32_bf16(a, b1, aZ, 0,0,0);
            aN = __builtin_amdgcn_mfma_f32_16x16x32_bf16(a, b2, aN, 0,0,0);
        }

        short* hANext = hA[(t + 1) & 1];
        #pragma unroll
        for (int p = 0; p < 4; ++p) {
            int row = q * 4 + p;
            float r_ = sigmoid_f(giR[p] + aR[p] + bhr);
            float z_ = sigmoid_f(giZ[p] + aZ[p] + bhz);
            float n_ = tanh_fast(giN[p] + r_ * (aN[p] + bhn));
            float hn = (1.f - z_) * n_ + z_ * hreg[p];
            hreg[p] = hn;
            hANext[row * PADA + u] = f2bf(hn);
        }
        __syncthreads();
    }

    #pragma unroll
    for (int p = 0; p < 4; ++p) {
        int s = sblock + q * 4 + p;
        hlast[s * 256 + u] = hreg[p];
    }
}

// ---------------------------------------------------------------------------
// tail: g = [f.max(1)|f.mean(1)|f.min(1)|hlast], fc1+relu, fc2
// ---------------------------------------------------------------------------
__global__ __launch_bounds__(256) void tail_kernel(
        const float* __restrict__ f, const float* __restrict__ hlast,
        const float* __restrict__ fc1Wt, const float* __restrict__ fc1b,
        const float* __restrict__ fc2W, const float* __restrict__ fc2b,
        float* __restrict__ out) {
    __shared__ float g_lds[FCIN_];
    __shared__ float red[256];
    const int tid = threadIdx.x;
    const int b = blockIdx.x;
    for (int i = tid; i < INTER_; i += 256) {
        float mx = -1e30f, mn = 1e30f, sm = 0.f;
        for (int t = 0; t < 64; ++t) {
            float v = f[(b * 64 + t) * INTER_ + i];
            mx = fmaxf(mx, v); mn = fminf(mn, v); sm += v;
        }
        g_lds[i] = mx;
        g_lds[INTER_ + i] = sm * (1.f / 64.f);
        g_lds[2 * INTER_ + i] = mn;
    }
    g_lds[3 * INTER_ + tid] = hlast[b * 256 + tid];
    __syncthreads();
    float acc = fc1b[tid];
    for (int i = 0; i < FCIN_; ++i)
        acc = fmaf(g_lds[i], fc1Wt[i * 256 + tid], acc);
    float hv = fmaxf(acc, 0.f);
    red[tid] = hv * fc2W[tid];
    __syncthreads();
    if (tid == 0) {
        float s = fc2b[0];
        for (int i = 0; i < 256; ++i) s += red[i];
        out[b] = s;
    }
}

// ---------------------------------------------------------------------------
extern "C" void kernel_launch(void* const* d_in, const int* in_sizes, int n_in,
                              void* d_out, int out_size, void* d_ws, size_t ws_size,
                              hipStream_t stream) {
    const float* x1     = (const float*)d_in[0];
    const float* states = (const float*)d_in[1];
    const int*   perm1  = (const int*)d_in[2];
    const int*   perm2  = (const int*)d_in[3];
    const float* Wih2   = (const float*)d_in[4];
    const float* Whh2   = (const float*)d_in[5];
    const float* bih2   = (const float*)d_in[6];
    const float* bhh2   = (const float*)d_in[7];
    const float* Wih1   = (const float*)d_in[8];
    const float* Whh1   = (const float*)d_in[9];
    const float* bih1   = (const float*)d_in[10];
    const float* bhh1   = (const float*)d_in[11];
    const float* fc1W   = (const float*)d_in[12];
    const float* fc1b   = (const float*)d_in[13];
    const float* fc2W   = (const float*)d_in[14];
    const float* fc2b   = (const float*)d_in[15];
    float* out = (float*)d_out;

    float* ws = (float*)d_ws;
    short* Bfrag  = (short*)ws;                 // 245760 bf16 -> 122880 floats
    short* Bfrag1 = (short*)(ws + 122880);      // 196608 bf16 -> 98304 floats
    float* fc1Wt  = ws + 122880 + 98304;        // 765952
    float* f      = fc1Wt + FCIN_ * 256;        // 1867776
    float* xw1    = f + 2048 * INTER_;          // 1572864
    float* hlast  = xw1 + 2048 * G3_;           // 8192

    prep_kernel<<<dim3(2992), 256, 0, stream>>>(Whh2, Wih2, Whh1, fc1W,
                                                Bfrag, Bfrag1, fc1Wt);
    reduce_states_kernel<<<dim3(512), 256, 0, stream>>>(states, x1, f);
    gru2d_mfma<<<dim3(256), 1024, 0, stream>>>(states, perm1, perm2, Bfrag,
                                               bih2, bhh2, f);
    gemm_xw1<<<dim3(12, 32), 256, 0, stream>>>(f, Wih1, bih1, xw1);
    gru1d_mfma<<<dim3(2), 1024, 0, stream>>>(xw1, Bfrag1, bhh1, hlast);
    tail_kernel<<<dim3(32), 256, 0, stream>>>(f, hlast, fc1Wt, fc1b, fc2W, fc2b, out);
}

// Round 6
// 806.467 us; speedup vs baseline: 1.0170x; 1.0170x over previous
//
#include <hip/hip_runtime.h>
#include <cmath>

#define B_ 32
#define N_ 64
#define H_ 256
#define G3_ 768           // 3*H
#define INTER_ 912        // 2H + 6C + C1
#define FCIN_ 2992        // 3*INTER + H

#define PADA 264          // hA row stride (bf16 elems), 528 B (16B-aligned)
#define PADX 72           // xA row stride (bf16 elems), 144 B

typedef __attribute__((ext_vector_type(8))) short short8;
typedef __attribute__((ext_vector_type(4))) float float4v;

__device__ __forceinline__ float sigmoid_f(float x) {
    return __fdividef(1.0f, 1.0f + __expf(-x));
}
__device__ __forceinline__ float tanh_fast(float x) {
    x = fminf(fmaxf(x, -15.f), 15.f);
    float e = __expf(2.f * x);
    return 1.f - __fdividef(2.f, e + 1.f);
}
__device__ __forceinline__ unsigned f2bf_bits(float x) {
    unsigned u = __float_as_uint(x);
    return (u + 0x7fffu + ((u >> 16) & 1u)) >> 16;
}
__device__ __forceinline__ short f2bf(float x) { return (short)f2bf_bits(x); }

// ---------------------------------------------------------------------------
// prep: (a) Bfrag  = gru2d weights, fragment-major bf16 (layout verified R2)
//       (b) Bfrag1 = gru1d Whh, same fragment-major pack (8 kt)
//       (c) fc1Wt transpose
// Fragment layout: [kt][ntile(48)][lane(64)][j(8)] bf16; value = W[n][k] with
// n = ntile*16 + (lane&15), k = kt*32 + (lane>>4)*8 + j.
// ---------------------------------------------------------------------------
__global__ __launch_bounds__(256) void prep_kernel(
        const float* __restrict__ Whh2, const float* __restrict__ Wih2,
        const float* __restrict__ Whh1, const float* __restrict__ fc1W,
        short* __restrict__ Bfrag, short* __restrict__ Bfrag1,
        float* __restrict__ fc1Wt) {
    int idx = blockIdx.x * 256 + threadIdx.x;
    if (idx < 10 * 48 * 64 * 8) {
        int j = idx & 7, lane = (idx >> 3) & 63, tile = idx >> 9;
        int nt = tile % 48, kt = tile / 48;
        int n = nt * 16 + (lane & 15);
        int kb = (lane >> 4) * 8 + j;
        float v = (kt < 8) ? Whh2[n * 256 + kt * 32 + kb]
                           : Wih2[n * 64 + (kt - 8) * 32 + kb];
        Bfrag[idx] = f2bf(v);
    }
    if (idx < 8 * 48 * 64 * 8) {
        int j = idx & 7, lane = (idx >> 3) & 63, tile = idx >> 9;
        int nt = tile % 48, kt = tile / 48;
        int n = nt * 16 + (lane & 15);
        int k = kt * 32 + (lane >> 4) * 8 + j;
        Bfrag1[idx] = f2bf(Whh1[n * 256 + k]);
    }
    if (idx < FCIN_ * 256) {
        int o = idx & 255, i = idx >> 8;
        fc1Wt[idx] = fc1W[o * FCIN_ + i];
    }
}

// ---------------------------------------------------------------------------
// reduce_states: d[] reductions + x1 copy -> f[:, 0:400]
// ---------------------------------------------------------------------------
__global__ __launch_bounds__(256) void reduce_states_kernel(
        const float* __restrict__ states, const float* __restrict__ x1,
        float* __restrict__ f) {
    const int c = threadIdx.x & 63;
    const int bj = blockIdx.x * 4 + (threadIdx.x >> 6);
    const int b = bj >> 6, j = bj & 63;
    const float* p1 = states + b * 262144 + j * 64 + c;
    const float* p2 = states + b * 262144 + j * 4096 + c;
    float mx1 = -1e30f, mn1 = 1e30f, sm1 = 0.f;
    float mx2 = -1e30f, mn2 = 1e30f, sm2 = 0.f;
    #pragma unroll 8
    for (int n = 0; n < 64; ++n) {
        float v = p1[n * 4096];
        mx1 = fmaxf(mx1, v); mn1 = fminf(mn1, v); sm1 += v;
    }
    #pragma unroll 8
    for (int m = 0; m < 64; ++m) {
        float v = p2[m * 64];
        mx2 = fmaxf(mx2, v); mn2 = fminf(mn2, v); sm2 += v;
    }
    float* fr = f + bj * INTER_;
    fr[16 + c]  = mx1;  fr[80 + c]  = sm1 * (1.f / 64.f);  fr[144 + c] = mn1;
    fr[208 + c] = mx2;  fr[272 + c] = sm2 * (1.f / 64.f);  fr[336 + c] = mn2;
    if (c < 16) fr[c] = x1[bj * 16 + c];
}

// ---------------------------------------------------------------------------
// gru2d via MFMA bf16, 16-wave edition. 256 blocks x 1024 threads.
// __launch_bounds__(1024, 4): min 4 waves/EU -> VGPR cap 128 (R5's implicit
// 64-reg target spilled Bres to scratch: +10 MB WRITE_SIZE, 341 us).
// Wave w owns 3 N-tiles (r: w, z: 16+w, n: 32+w); thread owns unit u=16w+m,
// rows q*4..q*4+3, all four preacts in own accumulators. B: kt0..5 in 72
// VGPRs, kt6..7 in 96 KB LDS, kt8..9 (x-part) VMEM per step (L2-hot).
// hA double-buffered -> ONE barrier per step. x-gather: 1 load/thread/step.
// ---------------------------------------------------------------------------
__global__ __launch_bounds__(1024, 4) void gru2d_mfma(
        const float* __restrict__ states,
        const int* __restrict__ perm1, const int* __restrict__ perm2,
        const short* __restrict__ Bfrag,
        const float* __restrict__ bih, const float* __restrict__ bhh,
        float* __restrict__ f) {
    __shared__ short hA[2][16 * PADA];     // 16896 B, double-buffered
    __shared__ short xA[2][16 * PADX];     // 4608 B, double-buffered
    __shared__ short8 Blds[2 * 48 * 64];   // 98304 B: kt 6,7
    __shared__ int perms[1024];            // 4096 B

    const int tid = threadIdx.x;
    const int lane = tid & 63;
    const int w = tid >> 6;                // wave 0..15
    const int m = lane & 15;
    const int q = lane >> 4;
    const bool sd2 = blockIdx.x >= 128;
    const int sblock = (blockIdx.x & 127) * 16;

    // perms: thread tid serves (r = tid>>6, t = tid&63); only its own wave
    // reads perms[w*64 + t], so no barrier needed for the t=0 gather below.
    {
        int r = tid >> 6, t = tid & 63;
        int qq = (sblock + r) & 63;
        perms[tid] = sd2 ? perm2[qq * 64 + t] : perm1[qq * 64 + t];
    }
    for (int i = tid; i < 16 * PADA; i += 1024) hA[0][i] = 0;
    {   // Blds <- kt 6,7 slice of Bfrag (contiguous)
        const uint4* src = (const uint4*)(Bfrag + 6 * 48 * 64 * 8);
        uint4* dst = (uint4*)Blds;
        #pragma unroll
        for (int rep = 0; rep < 6; ++rep)
            dst[tid + rep * 1024] = src[tid + rep * 1024];
    }

    const short8* Bf8 = (const short8*)Bfrag;
    short8 Bres[18];                       // kt0..5 x {r,z,n} tiles
    #pragma unroll
    for (int kt = 0; kt < 6; ++kt) {
        Bres[kt * 3 + 0] = Bf8[(kt * 48 + w) * 64 + lane];
        Bres[kt * 3 + 1] = Bf8[(kt * 48 + 16 + w) * 64 + lane];
        Bres[kt * 3 + 2] = Bf8[(kt * 48 + 32 + w) * 64 + lane];
    }

    const int u = 16 * w + m;
    const float br  = bih[u] + bhh[u];
    const float bz  = bih[256 + u] + bhh[256 + u];
    const float bnx = bih[512 + u];
    const float bnh = bhh[512 + u];

    float4v hreg = {0.f, 0.f, 0.f, 0.f};

    // gather geometry for this thread (row r == wave id, col c == lane)
    const int gr = w, gc = lane;
    const int gs = sblock + gr, gb = gs >> 6, gq = gs & 63;
    const int xdst = gr * PADX + gc;

    {   // stage x for t=0
        int p = perms[gr * 64 + 0];
        int src = sd2 ? ((gb * 64 + p) * 64 + gq) * 64 + gc
                      : ((gb * 64 + gq) * 64 + p) * 64 + gc;
        xA[0][xdst] = f2bf(states[src]);
    }
    __syncthreads();

    for (int t = 0; t < 64; ++t) {
        // issue next-step x gather early (lands during MFMA phase)
        float xg = 0.f;
        if (t + 1 < 64) {
            int p = perms[gr * 64 + t + 1];
            int src = sd2 ? ((gb * 64 + p) * 64 + gq) * 64 + gc
                          : ((gb * 64 + gq) * 64 + p) * 64 + gc;
            xg = states[src];
        }

        float4v aR  = {0.f,0.f,0.f,0.f}, aZ  = {0.f,0.f,0.f,0.f};
        float4v aNh = {0.f,0.f,0.f,0.f}, aNx = {0.f,0.f,0.f,0.f};

        const short* hACur = hA[t & 1];
        // h-phase, VGPR-resident kt0..5
        #pragma unroll
        for (int kt = 0; kt < 6; ++kt) {
            short8 a = *(const short8*)(hACur + m * PADA + kt * 32 + q * 8);
            aR  = __builtin_amdgcn_mfma_f32_16x16x32_bf16(a, Bres[kt*3+0], aR, 0,0,0);
            aZ  = __builtin_amdgcn_mfma_f32_16x16x32_bf16(a, Bres[kt*3+1], aZ, 0,0,0);
            aNh = __builtin_amdgcn_mfma_f32_16x16x32_bf16(a, Bres[kt*3+2], aNh, 0,0,0);
        }
        // x-part B loads, batch kt8 (cover with LDS-B phase)
        short8 bx80 = Bf8[(8 * 48 + w) * 64 + lane];
        short8 bx81 = Bf8[(8 * 48 + 16 + w) * 64 + lane];
        short8 bx82 = Bf8[(8 * 48 + 32 + w) * 64 + lane];
        // h-phase, LDS-resident kt6,7
        #pragma unroll
        for (int ktL = 0; ktL < 2; ++ktL) {
            short8 a = *(const short8*)(hACur + m * PADA + (6 + ktL) * 32 + q * 8);
            short8 b0 = Blds[(ktL * 48 + w) * 64 + lane];
            short8 b1 = Blds[(ktL * 48 + 16 + w) * 64 + lane];
            short8 b2 = Blds[(ktL * 48 + 32 + w) * 64 + lane];
            aR  = __builtin_amdgcn_mfma_f32_16x16x32_bf16(a, b0, aR, 0,0,0);
            aZ  = __builtin_amdgcn_mfma_f32_16x16x32_bf16(a, b1, aZ, 0,0,0);
            aNh = __builtin_amdgcn_mfma_f32_16x16x32_bf16(a, b2, aNh, 0,0,0);
        }
        // x-part B loads, batch kt9
        short8 bx90 = Bf8[(9 * 48 + w) * 64 + lane];
        short8 bx91 = Bf8[(9 * 48 + 16 + w) * 64 + lane];
        short8 bx92 = Bf8[(9 * 48 + 32 + w) * 64 + lane];
        // x-phase kt8,9
        {
            const short* xACur = xA[t & 1];
            short8 a8 = *(const short8*)(xACur + m * PADX + q * 8);
            aR  = __builtin_amdgcn_mfma_f32_16x16x32_bf16(a8, bx80, aR, 0,0,0);
            aZ  = __builtin_amdgcn_mfma_f32_16x16x32_bf16(a8, bx81, aZ, 0,0,0);
            aNx = __builtin_amdgcn_mfma_f32_16x16x32_bf16(a8, bx82, aNx, 0,0,0);
            short8 a9 = *(const short8*)(xACur + m * PADX + 32 + q * 8);
            aR  = __builtin_amdgcn_mfma_f32_16x16x32_bf16(a9, bx90, aR, 0,0,0);
            aZ  = __builtin_amdgcn_mfma_f32_16x16x32_bf16(a9, bx91, aZ, 0,0,0);
            aNx = __builtin_amdgcn_mfma_f32_16x16x32_bf16(a9, bx92, aNx, 0,0,0);
        }

        // commit next-step x to the other buffer
        if (t + 1 < 64) xA[(t + 1) & 1][xdst] = f2bf(xg);

        // register-local GRU update; write h(t+1) into the other hA buffer
        short* hANext = hA[(t + 1) & 1];
        #pragma unroll
        for (int p = 0; p < 4; ++p) {
            int row = q * 4 + p;
            float r_ = sigmoid_f(aR[p] + br);
            float z_ = sigmoid_f(aZ[p] + bz);
            float n_ = tanh_fast(aNx[p] + bnx + r_ * (aNh[p] + bnh));
            float hn = (1.f - z_) * n_ + z_ * hreg[p];
            hreg[p] = hn;
            hANext[row * PADA + u] = f2bf(hn);
        }
        __syncthreads();   // h(t+1), x(t+1) visible; everyone leaves step t
    }

    const int off = sd2 ? 656 : 400;
    #pragma unroll
    for (int p = 0; p < 4; ++p) {
        int s = sblock + q * 4 + p;
        f[s * INTER_ + off + u] = hreg[p];
    }
}

// ---------------------------------------------------------------------------
// xw1[2048][768] = f[2048][912] @ Wih1^T + bih1  (fp32 tiled GEMM)
// ---------------------------------------------------------------------------
__global__ __launch_bounds__(256) void gemm_xw1(
        const float* __restrict__ f, const float* __restrict__ Wih,
        const float* __restrict__ bih, float* __restrict__ xw) {
    __shared__ float As[64][17];
    __shared__ float Bs[64][17];
    const int tid = threadIdx.x;
    const int tn = blockIdx.x;
    const int tm = blockIdx.y;
    const int tx = tid & 15, ty = tid >> 4;
    float acc[4][4] = {};
    for (int k0 = 0; k0 < INTER_; k0 += 16) {
        for (int i = tid; i < 64 * 16; i += 256) {
            int r = i >> 4, kk = i & 15;
            As[r][kk] = f[(tm * 64 + r) * INTER_ + k0 + kk];
            Bs[r][kk] = Wih[(tn * 64 + r) * INTER_ + k0 + kk];
        }
        __syncthreads();
        #pragma unroll
        for (int kk = 0; kk < 16; ++kk) {
            float a[4], bb[4];
            #pragma unroll
            for (int i = 0; i < 4; ++i) a[i] = As[ty * 4 + i][kk];
            #pragma unroll
            for (int j = 0; j < 4; ++j) bb[j] = Bs[tx * 4 + j][kk];
            #pragma unroll
            for (int i = 0; i < 4; ++i)
                #pragma unroll
                for (int j = 0; j < 4; ++j)
                    acc[i][j] = fmaf(a[i], bb[j], acc[i][j]);
        }
        __syncthreads();
    }
    #pragma unroll
    for (int i = 0; i < 4; ++i) {
        int row = tm * 64 + ty * 4 + i;
        #pragma unroll
        for (int j = 0; j < 4; ++j) {
            int col = tn * 64 + tx * 4 + j;
            xw[row * G3_ + col] = acc[i][j] + bih[col];
        }
    }
}

// ---------------------------------------------------------------------------
// gru1d via MFMA bf16, 16-wave edition. 2 blocks x 1024 threads;
// __launch_bounds__(1024, 4) -> VGPR cap 128, no spills (see gru2d note).
// ---------------------------------------------------------------------------
__global__ __launch_bounds__(1024, 4) void gru1d_mfma(
        const float* __restrict__ xw, const short* __restrict__ Bfrag1,
        const float* __restrict__ bhh, float* __restrict__ hlast) {
    __shared__ short hA[2][16 * PADA];
    __shared__ short8 Blds[2 * 48 * 64];   // kt 6,7

    const int tid = threadIdx.x;
    const int lane = tid & 63;
    const int w = tid >> 6;
    const int m = lane & 15;
    const int q = lane >> 4;
    const int sblock = blockIdx.x * 16;

    for (int i = tid; i < 16 * PADA; i += 1024) hA[0][i] = 0;
    {
        const uint4* src = (const uint4*)(Bfrag1 + 6 * 48 * 64 * 8);
        uint4* dst = (uint4*)Blds;
        #pragma unroll
        for (int rep = 0; rep < 6; ++rep)
            dst[tid + rep * 1024] = src[tid + rep * 1024];
    }
    const short8* Bf8 = (const short8*)Bfrag1;
    short8 Bres[18];
    #pragma unroll
    for (int kt = 0; kt < 6; ++kt) {
        Bres[kt * 3 + 0] = Bf8[(kt * 48 + w) * 64 + lane];
        Bres[kt * 3 + 1] = Bf8[(kt * 48 + 16 + w) * 64 + lane];
        Bres[kt * 3 + 2] = Bf8[(kt * 48 + 32 + w) * 64 + lane];
    }

    const int u = 16 * w + m;
    const float bhr = bhh[u], bhz = bhh[256 + u], bhn = bhh[512 + u];

    float4v hreg = {0.f, 0.f, 0.f, 0.f};
    __syncthreads();

    for (int t = 0; t < 64; ++t) {
        // prefetch gi (L2-hot, covered by the MFMA phase)
        float giR[4], giZ[4], giN[4];
        #pragma unroll
        for (int p = 0; p < 4; ++p) {
            const float* g = xw + ((sblock + q * 4 + p) * 64 + t) * G3_;
            giR[p] = g[u]; giZ[p] = g[256 + u]; giN[p] = g[512 + u];
        }

        float4v aR = {0.f,0.f,0.f,0.f}, aZ = {0.f,0.f,0.f,0.f};
        float4v aN = {0.f,0.f,0.f,0.f};

        const short* hACur = hA[t & 1];
        #pragma unroll
        for (int kt = 0; kt < 6; ++kt) {
            short8 a = *(const short8*)(hACur + m * PADA + kt * 32 + q * 8);
            aR = __builtin_amdgcn_mfma_f32_16x16x32_bf16(a, Bres[kt*3+0], aR, 0,0,0);
            aZ = __builtin_amdgcn_mfma_f32_16x16x32_bf16(a, Bres[kt*3+1], aZ, 0,0,0);
            aN = __builtin_amdgcn_mfma_f32_16x16x32_bf16(a, Bres[kt*3+2], aN, 0,0,0);
        }
        #pragma unroll
        for (int ktL = 0; ktL < 2; ++ktL) {
            short8 a = *(const short8*)(hACur + m * PADA + (6 + ktL) * 32 + q * 8);
            short8 b0 = Blds[(ktL * 48 + w) * 64 + lane];
            short8 b1 = Blds[(ktL * 48 + 16 + w) * 64 + lane];
            short8 b2 = Blds[(ktL * 48 + 32 + w) * 64 + lane];
            aR = __builtin_amdgcn_mfma_f32_16x16x32_bf16(a, b0, aR, 0,0,0);
            aZ = __builtin_amdgcn_mfma_f32_16x16x32_bf16(a, b1, aZ, 0,0,0);
            aN = __builtin_amdgcn_mfma_f32_16x16x32_bf16(a, b2, aN, 0,0,0);
        }

        short* hANext = hA[(t + 1) & 1];
        #pragma unroll
        for (int p = 0; p < 4; ++p) {
            int row = q * 4 + p;
            float r_ = sigmoid_f(giR[p] + aR[p] + bhr);
            float z_ = sigmoid_f(giZ[p] + aZ[p] + bhz);
            float n_ = tanh_fast(giN[p] + r_ * (aN[p] + bhn));
            float hn = (1.f - z_) * n_ + z_ * hreg[p];
            hreg[p] = hn;
            hANext[row * PADA + u] = f2bf(hn);
        }
        __syncthreads();
    }

    #pragma unroll
    for (int p = 0; p < 4; ++p) {
        int s = sblock + q * 4 + p;
        hlast[s * 256 + u] = hreg[p];
    }
}

// ---------------------------------------------------------------------------
// tail: g = [f.max(1)|f.mean(1)|f.min(1)|hlast], fc1+relu, fc2
// ---------------------------------------------------------------------------
__global__ __launch_bounds__(256) void tail_kernel(
        const float* __restrict__ f, const float* __restrict__ hlast,
        const float* __restrict__ fc1Wt, const float* __restrict__ fc1b,
        const float* __restrict__ fc2W, const float* __restrict__ fc2b,
        float* __restrict__ out) {
    __shared__ float g_lds[FCIN_];
    __shared__ float red[256];
    const int tid = threadIdx.x;
    const int b = blockIdx.x;
    for (int i = tid; i < INTER_; i += 256) {
        float mx = -1e30f, mn = 1e30f, sm = 0.f;
        for (int t = 0; t < 64; ++t) {
            float v = f[(b * 64 + t) * INTER_ + i];
            mx = fmaxf(mx, v); mn = fminf(mn, v); sm += v;
        }
        g_lds[i] = mx;
        g_lds[INTER_ + i] = sm * (1.f / 64.f);
        g_lds[2 * INTER_ + i] = mn;
    }
    g_lds[3 * INTER_ + tid] = hlast[b * 256 + tid];
    __syncthreads();
    float acc = fc1b[tid];
    for (int i = 0; i < FCIN_; ++i)
        acc = fmaf(g_lds[i], fc1Wt[i * 256 + tid], acc);
    float hv = fmaxf(acc, 0.f);
    red[tid] = hv * fc2W[tid];
    __syncthreads();
    if (tid == 0) {
        float s = fc2b[0];
        for (int i = 0; i < 256; ++i) s += red[i];
        out[b] = s;
    }
}

// ---------------------------------------------------------------------------
extern "C" void kernel_launch(void* const* d_in, const int* in_sizes, int n_in,
                              void* d_out, int out_size, void* d_ws, size_t ws_size,
                              hipStream_t stream) {
    const float* x1     = (const float*)d_in[0];
    const float* states = (const float*)d_in[1];
    const int*   perm1  = (const int*)d_in[2];
    const int*   perm2  = (const int*)d_in[3];
    const float* Wih2   = (const float*)d_in[4];
    const float* Whh2   = (const float*)d_in[5];
    const float* bih2   = (const float*)d_in[6];
    const float* bhh2   = (const float*)d_in[7];
    const float* Wih1   = (const float*)d_in[8];
    const float* Whh1   = (const float*)d_in[9];
    const float* bih1   = (const float*)d_in[10];
    const float* bhh1   = (const float*)d_in[11];
    const float* fc1W   = (const float*)d_in[12];
    const float* fc1b   = (const float*)d_in[13];
    const float* fc2W   = (const float*)d_in[14];
    const float* fc2b   = (const float*)d_in[15];
    float* out = (float*)d_out;

    float* ws = (float*)d_ws;
    short* Bfrag  = (short*)ws;                 // 245760 bf16 -> 122880 floats
    short* Bfrag1 = (short*)(ws + 122880);      // 196608 bf16 -> 98304 floats
    float* fc1Wt  = ws + 122880 + 98304;        // 765952
    float* f      = fc1Wt + FCIN_ * 256;        // 1867776
    float* xw1    = f + 2048 * INTER_;          // 1572864
    float* hlast  = xw1 + 2048 * G3_;           // 8192

    prep_kernel<<<dim3(2992), 256, 0, stream>>>(Whh2, Wih2, Whh1, fc1W,
                                                Bfrag, Bfrag1, fc1Wt);
    reduce_states_kernel<<<dim3(512), 256, 0, stream>>>(states, x1, f);
    gru2d_mfma<<<dim3(256), 1024, 0, stream>>>(states, perm1, perm2, Bfrag,
                                               bih2, bhh2, f);
    gemm_xw1<<<dim3(12, 32), 256, 0, stream>>>(f, Wih1, bih1, xw1);
    gru1d_mfma<<<dim3(2), 1024, 0, stream>>>(xw1, Bfrag1, bhh1, hlast);
    tail_kernel<<<dim3(32), 256, 0, stream>>>(f, hlast, fc1Wt, fc1b, fc2W, fc2b, out);
}